// Round 1
// baseline (14350.951 us; speedup 1.0000x reference)
//
#include <hip/hip_runtime.h>
#include <hip/hip_bf16.h>
#include <cstddef>

// Problem constants
#define BB 64
#define TXX 128
#define TYY 48
#define NSS 47     // decoder steps = TY-1
#define EE 512
#define HH 1024
#define VV 32000
#define KGG 1536   // E + H

// ---------------------------------------------------------------------------
// Generic M=64 GEMM: C_partial[ks][64][Ntot] = A(64 x K_split) @ W(K x Ntot)
// Tile: 64 rows x 64 cols per workgroup, split-K via blockIdx.y.
// APROV: 0 = A is concat(emb[tok], h)  (gate GEMM, W given as 4 matrices)
//        1 = A is h                    (q = h @ attn_w)
//        2 = A is concat(h, ctx)       (lin GEMM)
// All W matrices have row stride 1024.
// ---------------------------------------------------------------------------
template <int APROV>
__global__ __launch_bounds__(256) void gemm_m64(
    const float* __restrict__ emb, const int* __restrict__ tok, int tokStride, int tstep,
    const float* __restrict__ hbuf, const float* __restrict__ ctxbuf,
    const float* __restrict__ W0, const float* __restrict__ W1,
    const float* __restrict__ W2, const float* __restrict__ W3,
    int Ntot, int splitLen, float* __restrict__ outp)
{
    __shared__ float As[16][68];   // [k][row], padded to avoid bank conflicts
    __shared__ float Ws[16][68];   // [k][col]

    const int tid = threadIdx.x;
    const int n0 = blockIdx.x * 64;

    const float* W = W0;
    if (APROV == 0) {
        int g = n0 >> 10;
        W = (g == 0) ? W0 : (g == 1) ? W1 : (g == 2) ? W2 : W3;
    }
    const int cc0 = (APROV == 0) ? (n0 & 1023) : n0;

    const int r_st = tid >> 2;          // staging row 0..63
    const int kq   = (tid & 3) * 4;     // staging k offset 0,4,8,12
    const int c_st = tid & 63;          // staging col
    const int kw   = tid >> 6;          // staging k base 0..3
    const int ridx = tid >> 4;          // compute: row group 0..15
    const int cidx = tid & 15;          // compute: col group 0..15

    const int kb0 = blockIdx.y * splitLen;
    const int kb1 = kb0 + splitLen;

    int tokr = 0;
    if (APROV == 0) tokr = tok[r_st * tokStride + tstep];

    float acc[4][4] = {};

    for (int kb = kb0; kb < kb1; kb += 16) {
        // stage A: 64 rows x 16 k  (each thread: 4 consecutive k of one row)
        #pragma unroll
        for (int j = 0; j < 4; j++) {
            int k = kb + kq + j;
            float a;
            if (APROV == 0) {
                a = (k < EE) ? emb[(size_t)tokr * EE + k]
                             : hbuf[r_st * HH + (k - EE)];
            } else if (APROV == 1) {
                a = hbuf[r_st * HH + k];
            } else {
                a = (k < HH) ? hbuf[r_st * HH + k]
                             : ctxbuf[r_st * HH + (k - HH)];
            }
            As[kq + j][r_st] = a;
        }
        // stage W: 16 k x 64 cols (coalesced)
        #pragma unroll
        for (int j = 0; j < 4; j++) {
            int kk = kw + j * 4;
            Ws[kk][c_st] = W[(size_t)(kb + kk) * 1024 + cc0 + c_st];
        }
        __syncthreads();

        #pragma unroll
        for (int kk = 0; kk < 16; kk++) {
            float4 av = *reinterpret_cast<const float4*>(&As[kk][ridx * 4]);
            float4 wv = *reinterpret_cast<const float4*>(&Ws[kk][cidx * 4]);
            float ar[4] = {av.x, av.y, av.z, av.w};
            float wr[4] = {wv.x, wv.y, wv.z, wv.w};
            #pragma unroll
            for (int i = 0; i < 4; i++)
                #pragma unroll
                for (int j = 0; j < 4; j++)
                    acc[i][j] += ar[i] * wr[j];
        }
        __syncthreads();
    }

    // write split-K partial: outp[(ks*64 + r) * Ntot + n]
    #pragma unroll
    for (int i = 0; i < 4; i++) {
        int r = ridx * 4 + i;
        float4 o = {acc[i][0], acc[i][1], acc[i][2], acc[i][3]};
        *reinterpret_cast<float4*>(
            &outp[((size_t)(blockIdx.y * 64 + r)) * Ntot + n0 + cidx * 4]) = o;
    }
}

// ---------------------------------------------------------------------------
// LSTM elementwise update: sums 4 split-K gate partials + bias, applies gates.
// gp layout: [4 splits][64 rows][4096 cols], col = gate*1024 + cc,
// gate order: 0=i, 1=f, 2=o, 3=c.
// ---------------------------------------------------------------------------
__global__ __launch_bounds__(256) void lstm_update(
    const float* __restrict__ gp,
    const float* __restrict__ bi, const float* __restrict__ bf,
    const float* __restrict__ bo, const float* __restrict__ bc,
    float* __restrict__ h, float* __restrict__ c, float* __restrict__ hs_slot)
{
    int idx = blockIdx.x * 256 + threadIdx.x;  // 0..65535
    int b = idx >> 10, cc = idx & 1023;
    float gi = bi[cc], gf = bf[cc], go = bo[cc], gc = bc[cc];
    #pragma unroll
    for (int s = 0; s < 4; s++) {
        const float* g0 = gp + ((size_t)(s * 64 + b)) * 4096;
        gi += g0[cc];
        gf += g0[1024 + cc];
        go += g0[2048 + cc];
        gc += g0[3072 + cc];
    }
    float F = 1.f / (1.f + expf(-gf));
    float I = 1.f / (1.f + expf(-gi));
    float O = 1.f / (1.f + expf(-go));
    float G = tanhf(gc);
    float cn = F * c[idx] + I * G;
    c[idx] = cn;
    float hn = O * tanhf(cn);
    h[idx] = hn;
    if (hs_slot) hs_slot[idx] = hn;
}

// ---------------------------------------------------------------------------
// Attention: per batch row b (one block each):
//   q = sum(qpart) + attn_b ; scores over 128 enc states; softmax; ctx.
// enc layout: [t][b][h]
// ---------------------------------------------------------------------------
__global__ __launch_bounds__(256) void attn_kernel(
    const float* __restrict__ qp, const float* __restrict__ attn_b,
    const float* __restrict__ enc, float* __restrict__ ctx)
{
    int b = blockIdx.x;
    int tid = threadIdx.x;
    __shared__ float q[1024];
    __shared__ float sc[128];
    __shared__ float smax_s, ssum_s;

    // q = attn_b + sum of 4 split-K partials
    for (int i = tid; i < 1024; i += 256) {
        float v = attn_b[i];
        #pragma unroll
        for (int s = 0; s < 4; s++) v += qp[((size_t)(s * 64 + b)) * 1024 + i];
        q[i] = v;
    }
    __syncthreads();

    int wave = tid >> 6, lane = tid & 63;
    // scores: wave w handles t in [w*32, w*32+32)
    for (int i = 0; i < 32; i++) {
        int t = wave * 32 + i;
        const float* e = enc + ((size_t)t * 64 + b) * 1024;
        float s = 0.f;
        #pragma unroll
        for (int j = 0; j < 16; j++) s += q[lane + j * 64] * e[lane + j * 64];
        #pragma unroll
        for (int o = 32; o > 0; o >>= 1) s += __shfl_down(s, o, 64);
        if (lane == 0) sc[t] = s;
    }
    __syncthreads();

    // softmax over 128 scores (wave 0)
    if (wave == 0) {
        float v = fmaxf(sc[lane], sc[lane + 64]);
        #pragma unroll
        for (int o = 32; o > 0; o >>= 1) v = fmaxf(v, __shfl_down(v, o, 64));
        if (lane == 0) smax_s = v;
    }
    __syncthreads();
    float mx = smax_s;
    if (wave == 0) {
        float e0 = expf(sc[lane] - mx), e1 = expf(sc[lane + 64] - mx);
        sc[lane] = e0; sc[lane + 64] = e1;
        float v = e0 + e1;
        #pragma unroll
        for (int o = 32; o > 0; o >>= 1) v += __shfl_down(v, o, 64);
        if (lane == 0) ssum_s = v;
    }
    __syncthreads();
    float inv = 1.f / ssum_s;

    // ctx[b][h] = sum_t aw[t] * enc[t][b][h]; thread owns 4 h
    int h0 = tid * 4;
    float4 acc = {0.f, 0.f, 0.f, 0.f};
    for (int t = 0; t < 128; t++) {
        float a = sc[t] * inv;
        float4 ev = *reinterpret_cast<const float4*>(
            enc + ((size_t)t * 64 + b) * 1024 + h0);
        acc.x += a * ev.x; acc.y += a * ev.y;
        acc.z += a * ev.z; acc.w += a * ev.w;
    }
    *reinterpret_cast<float4*>(&ctx[(size_t)b * 1024 + h0]) = acc;
}

// ---------------------------------------------------------------------------
// lin combine: prelogit[s][b][cc] = tanh(lin_b + sum of 4 lin partials)
// ---------------------------------------------------------------------------
__global__ __launch_bounds__(256) void lin_combine(
    const float* __restrict__ lp, const float* __restrict__ lin_b,
    float* __restrict__ pre, int sstep)
{
    int idx = blockIdx.x * 256 + threadIdx.x;
    int b = idx >> 10, cc = idx & 1023;
    float v = lin_b[cc];
    #pragma unroll
    for (int s = 0; s < 4; s++) v += lp[((size_t)(s * 64 + b)) * 1024 + cc];
    pre[((size_t)sstep * 64 + b) * 1024 + cc] = tanhf(v);
}

// ---------------------------------------------------------------------------
// Output projection: out[b][s][v] = prelogit[s*64+b][:] @ out_w + out_b
// M=3008 (one M-tile == one decoder step s), N=32000, K=1024.
// grid: (47 m-tiles, 500 n-tiles); blockIdx.x fastest => consecutive blocks
// share the same W column panel (L2 reuse).
// ---------------------------------------------------------------------------
__global__ __launch_bounds__(256) void gemm_out(
    const float* __restrict__ A, const float* __restrict__ W,
    const float* __restrict__ bias, float* __restrict__ out)
{
    __shared__ float As[16][68];
    __shared__ float Ws[16][68];
    int tid = threadIdx.x;
    int mtile = blockIdx.x;          // == decoder step s
    int v0 = blockIdx.y * 64;
    const int r_st = tid >> 2, kq = (tid & 3) * 4;
    const int c_st = tid & 63, kw = tid >> 6;
    const int ridx = tid >> 4, cidx = tid & 15;
    float acc[4][4] = {};

    for (int kb = 0; kb < 1024; kb += 16) {
        #pragma unroll
        for (int j = 0; j < 4; j++)
            As[kq + j][r_st] = A[(size_t)(mtile * 64 + r_st) * 1024 + kb + kq + j];
        #pragma unroll
        for (int j = 0; j < 4; j++) {
            int kk = kw + j * 4;
            Ws[kk][c_st] = W[(size_t)(kb + kk) * VV + v0 + c_st];
        }
        __syncthreads();
        #pragma unroll
        for (int kk = 0; kk < 16; kk++) {
            float4 av = *reinterpret_cast<const float4*>(&As[kk][ridx * 4]);
            float4 wv = *reinterpret_cast<const float4*>(&Ws[kk][cidx * 4]);
            float ar[4] = {av.x, av.y, av.z, av.w};
            float wr[4] = {wv.x, wv.y, wv.z, wv.w};
            #pragma unroll
            for (int i = 0; i < 4; i++)
                #pragma unroll
                for (int j = 0; j < 4; j++)
                    acc[i][j] += ar[i] * wr[j];
        }
        __syncthreads();
    }

    int s = mtile;
    #pragma unroll
    for (int i = 0; i < 4; i++) {
        int b = ridx * 4 + i;
        int v = v0 + cidx * 4;
        float4 o;
        o.x = acc[i][0] + bias[v];
        o.y = acc[i][1] + bias[v + 1];
        o.z = acc[i][2] + bias[v + 2];
        o.w = acc[i][3] + bias[v + 3];
        *reinterpret_cast<float4*>(&out[((size_t)b * NSS + s) * VV + v]) = o;
    }
}

// ---------------------------------------------------------------------------
extern "C" void kernel_launch(void* const* d_in, const int* in_sizes, int n_in,
                              void* d_out, int out_size, void* d_ws, size_t ws_size,
                              hipStream_t stream)
{
    const int*   x       = (const int*)d_in[0];
    const int*   y       = (const int*)d_in[1];
    const float* enc_emb = (const float*)d_in[2];
    const float* dec_emb = (const float*)d_in[3];
    const float* enc_wi  = (const float*)d_in[4];
    const float* enc_bi  = (const float*)d_in[5];
    const float* enc_wf  = (const float*)d_in[6];
    const float* enc_bf  = (const float*)d_in[7];
    const float* enc_wo  = (const float*)d_in[8];
    const float* enc_bo  = (const float*)d_in[9];
    const float* enc_wc  = (const float*)d_in[10];
    const float* enc_bc  = (const float*)d_in[11];
    const float* dec_wi  = (const float*)d_in[12];
    const float* dec_bi  = (const float*)d_in[13];
    const float* dec_wf  = (const float*)d_in[14];
    const float* dec_bf  = (const float*)d_in[15];
    const float* dec_wo  = (const float*)d_in[16];
    const float* dec_bo  = (const float*)d_in[17];
    const float* dec_wc  = (const float*)d_in[18];
    const float* dec_bc  = (const float*)d_in[19];
    const float* attn_w  = (const float*)d_in[20];
    const float* attn_b  = (const float*)d_in[21];
    const float* lin_w   = (const float*)d_in[22];
    const float* lin_b   = (const float*)d_in[23];
    const float* out_w   = (const float*)d_in[24];
    const float* out_b   = (const float*)d_in[25];

    float* ws = (float*)d_ws;
    float* h      = ws;                       // 64*1024
    float* c      = ws + 65536;               // 64*1024
    float* ctx    = ws + 131072;              // 64*1024
    float* enc_hs = ws + 196608;              // 128*64*1024 = 8388608
    float* gp     = enc_hs + 8388608;         // 4*64*4096  = 1048576
    float* qp     = gp + 1048576;             // 4*64*1024  = 262144
    float* lp     = qp + 262144;              // 4*64*1024  = 262144
    float* pre    = lp + 262144;              // 47*64*1024 = 3080192

    // zero h and c (contiguous)
    hipMemsetAsync(h, 0, (size_t)2 * 65536 * sizeof(float), stream);

    // ---------------- encoder ----------------
    for (int t = 0; t < TXX; t++) {
        gemm_m64<0><<<dim3(64, 4), 256, 0, stream>>>(
            enc_emb, x, TXX, t, h, nullptr,
            enc_wi, enc_wf, enc_wo, enc_wc, 4096, 384, gp);
        lstm_update<<<dim3(256), 256, 0, stream>>>(
            gp, enc_bi, enc_bf, enc_bo, enc_bc, h, c,
            enc_hs + (size_t)t * 65536);
    }

    // ---------------- decoder ----------------
    for (int s = 0; s < NSS; s++) {
        gemm_m64<0><<<dim3(64, 4), 256, 0, stream>>>(
            dec_emb, y, TYY, s, h, nullptr,
            dec_wi, dec_wf, dec_wo, dec_wc, 4096, 384, gp);
        lstm_update<<<dim3(256), 256, 0, stream>>>(
            gp, dec_bi, dec_bf, dec_bo, dec_bc, h, c, nullptr);
        gemm_m64<1><<<dim3(16, 4), 256, 0, stream>>>(
            nullptr, nullptr, 0, 0, h, nullptr,
            attn_w, nullptr, nullptr, nullptr, 1024, 256, qp);
        attn_kernel<<<dim3(64), 256, 0, stream>>>(qp, attn_b, enc_hs, ctx);
        gemm_m64<2><<<dim3(16, 4), 256, 0, stream>>>(
            nullptr, nullptr, 0, 0, h, ctx,
            lin_w, nullptr, nullptr, nullptr, 1024, 512, lp);
        lin_combine<<<dim3(256), 256, 0, stream>>>(lp, lin_b, pre, s);
    }

    // ---------------- output projection ----------------
    gemm_out<<<dim3(NSS, VV / 64), 256, 0, stream>>>(pre, out_w, out_b, (float*)d_out);
}

// Round 2
// 11815.301 us; speedup vs baseline: 1.2146x; 1.2146x over previous
//
#include <hip/hip_runtime.h>
#include <hip/hip_bf16.h>
#include <cstddef>

// Problem constants
#define BB 64
#define TXX 128
#define TYY 48
#define NSS 47     // decoder steps = TY-1
#define EE 512
#define HH 1024
#define VV 32000

typedef _Float16 f16x8 __attribute__((ext_vector_type(8)));
typedef float f32x4 __attribute__((ext_vector_type(4)));
typedef unsigned short ush;

__device__ __forceinline__ ush f2h(float x) {
    _Float16 h = (_Float16)x;
    return __builtin_bit_cast(ush, h);
}

__device__ __forceinline__ void gload16(const void* g, void* l) {
    __builtin_amdgcn_global_load_lds(
        (const __attribute__((address_space(1))) unsigned int*)g,
        (__attribute__((address_space(3))) unsigned int*)l, 16, 0, 0);
}

// ---------------------------------------------------------------------------
// Generic M=64 fp32 GEMM for the recurrent chain (unchanged from round 0).
// ---------------------------------------------------------------------------
template <int APROV>
__global__ __launch_bounds__(256) void gemm_m64(
    const float* __restrict__ emb, const int* __restrict__ tok, int tokStride, int tstep,
    const float* __restrict__ hbuf, const float* __restrict__ ctxbuf,
    const float* __restrict__ W0, const float* __restrict__ W1,
    const float* __restrict__ W2, const float* __restrict__ W3,
    int Ntot, int splitLen, float* __restrict__ outp)
{
    __shared__ float As[16][68];
    __shared__ float Ws[16][68];

    const int tid = threadIdx.x;
    const int n0 = blockIdx.x * 64;

    const float* W = W0;
    if (APROV == 0) {
        int g = n0 >> 10;
        W = (g == 0) ? W0 : (g == 1) ? W1 : (g == 2) ? W2 : W3;
    }
    const int cc0 = (APROV == 0) ? (n0 & 1023) : n0;

    const int r_st = tid >> 2;
    const int kq   = (tid & 3) * 4;
    const int c_st = tid & 63;
    const int kw   = tid >> 6;
    const int ridx = tid >> 4;
    const int cidx = tid & 15;

    const int kb0 = blockIdx.y * splitLen;
    const int kb1 = kb0 + splitLen;

    int tokr = 0;
    if (APROV == 0) tokr = tok[r_st * tokStride + tstep];

    float acc[4][4] = {};

    for (int kb = kb0; kb < kb1; kb += 16) {
        #pragma unroll
        for (int j = 0; j < 4; j++) {
            int k = kb + kq + j;
            float a;
            if (APROV == 0) {
                a = (k < EE) ? emb[(size_t)tokr * EE + k]
                             : hbuf[r_st * HH + (k - EE)];
            } else if (APROV == 1) {
                a = hbuf[r_st * HH + k];
            } else {
                a = (k < HH) ? hbuf[r_st * HH + k]
                             : ctxbuf[r_st * HH + (k - HH)];
            }
            As[kq + j][r_st] = a;
        }
        #pragma unroll
        for (int j = 0; j < 4; j++) {
            int kk = kw + j * 4;
            Ws[kk][c_st] = W[(size_t)(kb + kk) * 1024 + cc0 + c_st];
        }
        __syncthreads();

        #pragma unroll
        for (int kk = 0; kk < 16; kk++) {
            float4 av = *reinterpret_cast<const float4*>(&As[kk][ridx * 4]);
            float4 wv = *reinterpret_cast<const float4*>(&Ws[kk][cidx * 4]);
            float ar[4] = {av.x, av.y, av.z, av.w};
            float wr[4] = {wv.x, wv.y, wv.z, wv.w};
            #pragma unroll
            for (int i = 0; i < 4; i++)
                #pragma unroll
                for (int j = 0; j < 4; j++)
                    acc[i][j] += ar[i] * wr[j];
        }
        __syncthreads();
    }

    #pragma unroll
    for (int i = 0; i < 4; i++) {
        int r = ridx * 4 + i;
        float4 o = {acc[i][0], acc[i][1], acc[i][2], acc[i][3]};
        *reinterpret_cast<float4*>(
            &outp[((size_t)(blockIdx.y * 64 + r)) * Ntot + n0 + cidx * 4]) = o;
    }
}

// ---------------------------------------------------------------------------
// LSTM elementwise update (unchanged).
// ---------------------------------------------------------------------------
__global__ __launch_bounds__(256) void lstm_update(
    const float* __restrict__ gp,
    const float* __restrict__ bi, const float* __restrict__ bf,
    const float* __restrict__ bo, const float* __restrict__ bc,
    float* __restrict__ h, float* __restrict__ c, float* __restrict__ hs_slot)
{
    int idx = blockIdx.x * 256 + threadIdx.x;
    int b = idx >> 10, cc = idx & 1023;
    float gi = bi[cc], gf = bf[cc], go = bo[cc], gc = bc[cc];
    #pragma unroll
    for (int s = 0; s < 4; s++) {
        const float* g0 = gp + ((size_t)(s * 64 + b)) * 4096;
        gi += g0[cc];
        gf += g0[1024 + cc];
        go += g0[2048 + cc];
        gc += g0[3072 + cc];
    }
    float F = 1.f / (1.f + expf(-gf));
    float I = 1.f / (1.f + expf(-gi));
    float O = 1.f / (1.f + expf(-go));
    float G = tanhf(gc);
    float cn = F * c[idx] + I * G;
    c[idx] = cn;
    float hn = O * tanhf(cn);
    h[idx] = hn;
    if (hs_slot) hs_slot[idx] = hn;
}

// ---------------------------------------------------------------------------
// Attention (unchanged). enc layout: [t][b][h]
// ---------------------------------------------------------------------------
__global__ __launch_bounds__(256) void attn_kernel(
    const float* __restrict__ qp, const float* __restrict__ attn_b,
    const float* __restrict__ enc, float* __restrict__ ctx)
{
    int b = blockIdx.x;
    int tid = threadIdx.x;
    __shared__ float q[1024];
    __shared__ float sc[128];
    __shared__ float smax_s, ssum_s;

    for (int i = tid; i < 1024; i += 256) {
        float v = attn_b[i];
        #pragma unroll
        for (int s = 0; s < 4; s++) v += qp[((size_t)(s * 64 + b)) * 1024 + i];
        q[i] = v;
    }
    __syncthreads();

    int wave = tid >> 6, lane = tid & 63;
    for (int i = 0; i < 32; i++) {
        int t = wave * 32 + i;
        const float* e = enc + ((size_t)t * 64 + b) * 1024;
        float s = 0.f;
        #pragma unroll
        for (int j = 0; j < 16; j++) s += q[lane + j * 64] * e[lane + j * 64];
        #pragma unroll
        for (int o = 32; o > 0; o >>= 1) s += __shfl_down(s, o, 64);
        if (lane == 0) sc[t] = s;
    }
    __syncthreads();

    if (wave == 0) {
        float v = fmaxf(sc[lane], sc[lane + 64]);
        #pragma unroll
        for (int o = 32; o > 0; o >>= 1) v = fmaxf(v, __shfl_down(v, o, 64));
        if (lane == 0) smax_s = v;
    }
    __syncthreads();
    float mx = smax_s;
    if (wave == 0) {
        float e0 = expf(sc[lane] - mx), e1 = expf(sc[lane + 64] - mx);
        sc[lane] = e0; sc[lane + 64] = e1;
        float v = e0 + e1;
        #pragma unroll
        for (int o = 32; o > 0; o >>= 1) v += __shfl_down(v, o, 64);
        if (lane == 0) ssum_s = v;
    }
    __syncthreads();
    float inv = 1.f / ssum_s;

    int h0 = tid * 4;
    float4 acc = {0.f, 0.f, 0.f, 0.f};
    for (int t = 0; t < 128; t++) {
        float a = sc[t] * inv;
        float4 ev = *reinterpret_cast<const float4*>(
            enc + ((size_t)t * 64 + b) * 1024 + h0);
        acc.x += a * ev.x; acc.y += a * ev.y;
        acc.z += a * ev.z; acc.w += a * ev.w;
    }
    *reinterpret_cast<float4*>(&ctx[(size_t)b * 1024 + h0]) = acc;
}

// ---------------------------------------------------------------------------
// lin combine: prelogit (f16) [s*64+b][cc] = tanh(lin_b + sum of partials)
// ---------------------------------------------------------------------------
__global__ __launch_bounds__(256) void lin_combine(
    const float* __restrict__ lp, const float* __restrict__ lin_b,
    ush* __restrict__ preh, int sstep)
{
    int idx = blockIdx.x * 256 + threadIdx.x;
    int b = idx >> 10, cc = idx & 1023;
    float v = lin_b[cc];
    #pragma unroll
    for (int s = 0; s < 4; s++) v += lp[((size_t)(s * 64 + b)) * 1024 + cc];
    preh[((size_t)sstep * 64 + b) * 1024 + cc] = f2h(tanhf(v));
}

// ---------------------------------------------------------------------------
// Transpose + f32->f16 convert: W [Krows][Ncols] f32 -> Wt [Ncols][Krows] f16
// ---------------------------------------------------------------------------
__global__ __launch_bounds__(256) void transpose_w(
    const float* __restrict__ W, ush* __restrict__ Wt, int Krows, int Ncols)
{
    __shared__ float t[32][33];
    int v0 = blockIdx.x * 32, k0 = blockIdx.y * 32;
    int tv = threadIdx.x & 31, tk = threadIdx.x >> 5;   // tk 0..7
    #pragma unroll
    for (int i = 0; i < 4; i++) {
        int k = tk * 4 + i;
        t[k][tv] = W[(size_t)(k0 + k) * Ncols + v0 + tv];
    }
    __syncthreads();
    #pragma unroll
    for (int i = 0; i < 4; i++) {
        int v = tk * 4 + i;
        Wt[(size_t)(v0 + v) * Krows + k0 + tv] = f2h(t[tv][v]);
    }
}

// ---------------------------------------------------------------------------
// f16 MFMA GEMM: C = A @ Bt^T, A [Mpad][K] f16 row-major, Bt [N][K] f16
// (both K-contiguous). 128x128 tile, 4 waves, each wave 64x64 (4x4 frags of
// 16x16x32). global_load_lds width-16 staging, 2-barrier K-loop (m97 style).
// MODE 1: out-projection epilogue — out[b][s][v] permute + bias + row guard.
// ---------------------------------------------------------------------------
template <int MODE>
__global__ __launch_bounds__(256) void gemm_f16(
    const ush* __restrict__ A, const ush* __restrict__ Bt,
    const float* __restrict__ bias, float* __restrict__ C,
    int K, int Nld, int Mvalid)
{
    __shared__ ush As[128 * 64];
    __shared__ ush Bs[128 * 64];
    const int tid = threadIdx.x;
    const int lane = tid & 63;
    const int w = tid >> 6;          // wave 0..3
    const int wm = w >> 1, wn = w & 1;
    const int m0 = blockIdx.x * 128;
    const int n0 = blockIdx.y * 128;

    f32x4 acc[4][4] = {};

    const int srow = w * 32 + (lane >> 3);      // staging row (+c*8)
    const int skoff = (lane & 7) * 8;           // staging k offset (f16 units)

    for (int kb = 0; kb < K; kb += 64) {
        #pragma unroll
        for (int c = 0; c < 4; c++) {
            const ush* ga = A + (size_t)(m0 + srow + c * 8) * K + kb + skoff;
            gload16(ga, &As[(w * 4 + c) * 512]);
        }
        #pragma unroll
        for (int c = 0; c < 4; c++) {
            const ush* gb = Bt + (size_t)(n0 + srow + c * 8) * K + kb + skoff;
            gload16(gb, &Bs[(w * 4 + c) * 512]);
        }
        __syncthreads();

        #pragma unroll
        for (int kw = 0; kw < 2; kw++) {
            const int koff = kw * 32 + (lane >> 4) * 8;   // f16 units within row
            f16x8 af[4], bf[4];
            #pragma unroll
            for (int m = 0; m < 4; m++) {
                int row = wm * 64 + m * 16 + (lane & 15);
                af[m] = *(const f16x8*)&As[row * 64 + koff];
            }
            #pragma unroll
            for (int n = 0; n < 4; n++) {
                int row = wn * 64 + n * 16 + (lane & 15);
                bf[n] = *(const f16x8*)&Bs[row * 64 + koff];
            }
            #pragma unroll
            for (int m = 0; m < 4; m++)
                #pragma unroll
                for (int n = 0; n < 4; n++)
                    acc[m][n] = __builtin_amdgcn_mfma_f32_16x16x32_f16(
                        af[m], bf[n], acc[m][n], 0, 0, 0);
        }
        __syncthreads();
    }

    // epilogue: C/D layout col = lane&15, row = (lane>>4)*4 + reg
    #pragma unroll
    for (int n = 0; n < 4; n++) {
        int v = n0 + wn * 64 + n * 16 + (lane & 15);
        float bs = (MODE == 1) ? bias[v] : 0.f;
        #pragma unroll
        for (int m = 0; m < 4; m++) {
            int rbase = m0 + wm * 64 + m * 16 + (lane >> 4) * 4;
            #pragma unroll
            for (int r = 0; r < 4; r++) {
                int row = rbase + r;
                if (MODE == 1) {
                    if (row < 3008) {
                        int b = row & 63, s = row >> 6;
                        C[((size_t)b * NSS + s) * VV + v] = acc[m][n][r] + bs;
                    }
                } else {
                    if (row < Mvalid) C[(size_t)row * Nld + v] = acc[m][n][r];
                }
            }
        }
    }
}

// ---------------------------------------------------------------------------
extern "C" void kernel_launch(void* const* d_in, const int* in_sizes, int n_in,
                              void* d_out, int out_size, void* d_ws, size_t ws_size,
                              hipStream_t stream)
{
    const int*   x       = (const int*)d_in[0];
    const int*   y       = (const int*)d_in[1];
    const float* enc_emb = (const float*)d_in[2];
    const float* dec_emb = (const float*)d_in[3];
    const float* enc_wi  = (const float*)d_in[4];
    const float* enc_bi  = (const float*)d_in[5];
    const float* enc_wf  = (const float*)d_in[6];
    const float* enc_bf  = (const float*)d_in[7];
    const float* enc_wo  = (const float*)d_in[8];
    const float* enc_bo  = (const float*)d_in[9];
    const float* enc_wc  = (const float*)d_in[10];
    const float* enc_bc  = (const float*)d_in[11];
    const float* dec_wi  = (const float*)d_in[12];
    const float* dec_bi  = (const float*)d_in[13];
    const float* dec_wf  = (const float*)d_in[14];
    const float* dec_bf  = (const float*)d_in[15];
    const float* dec_wo  = (const float*)d_in[16];
    const float* dec_bo  = (const float*)d_in[17];
    const float* dec_wc  = (const float*)d_in[18];
    const float* dec_bc  = (const float*)d_in[19];
    const float* attn_w  = (const float*)d_in[20];
    const float* attn_b  = (const float*)d_in[21];
    const float* lin_w   = (const float*)d_in[22];
    const float* lin_b   = (const float*)d_in[23];
    const float* out_w   = (const float*)d_in[24];
    const float* out_b   = (const float*)d_in[25];

    float* ws = (float*)d_ws;
    float* h      = ws;                       // 64*1024
    float* c      = ws + 65536;               // 64*1024
    float* ctx    = ws + 131072;              // 64*1024
    float* enc_hs = ws + 196608;              // 128*64*1024
    float* gp     = enc_hs + 8388608;         // 4*64*4096
    float* qp     = gp + 1048576;             // 4*64*1024
    float* lp     = qp + 262144;              // 4*64*1024
    ush*   preh   = (ush*)(lp + 262144);      // 3072*1024 f16 (pad rows 3008..3071)
    ush*   Wt     = preh + (size_t)3072 * 1024;  // 32000*1024 f16

    hipMemsetAsync(h, 0, (size_t)2 * 65536 * sizeof(float), stream);

    // one-time: out_w [1024][32000] -> Wt [32000][1024] f16
    transpose_w<<<dim3(VV / 32, HH / 32), 256, 0, stream>>>(out_w, Wt, HH, VV);

    // ---------------- encoder ----------------
    for (int t = 0; t < TXX; t++) {
        gemm_m64<0><<<dim3(64, 4), 256, 0, stream>>>(
            enc_emb, x, TXX, t, h, nullptr,
            enc_wi, enc_wf, enc_wo, enc_wc, 4096, 384, gp);
        lstm_update<<<dim3(256), 256, 0, stream>>>(
            gp, enc_bi, enc_bf, enc_bo, enc_bc, h, c,
            enc_hs + (size_t)t * 65536);
    }

    // ---------------- decoder ----------------
    for (int s = 0; s < NSS; s++) {
        gemm_m64<0><<<dim3(64, 4), 256, 0, stream>>>(
            dec_emb, y, TYY, s, h, nullptr,
            dec_wi, dec_wf, dec_wo, dec_wc, 4096, 384, gp);
        lstm_update<<<dim3(256), 256, 0, stream>>>(
            gp, dec_bi, dec_bf, dec_bo, dec_bc, h, c, nullptr);
        gemm_m64<1><<<dim3(16, 4), 256, 0, stream>>>(
            nullptr, nullptr, 0, 0, h, nullptr,
            attn_w, nullptr, nullptr, nullptr, 1024, 256, qp);
        attn_kernel<<<dim3(64), 256, 0, stream>>>(qp, attn_b, enc_hs, ctx);
        gemm_m64<2><<<dim3(16, 4), 256, 0, stream>>>(
            nullptr, nullptr, 0, 0, h, ctx,
            lin_w, nullptr, nullptr, nullptr, 1024, 512, lp);
        lin_combine<<<dim3(256), 256, 0, stream>>>(lp, lin_b, preh, s);
    }

    // ---------------- output projection (f16 MFMA) ----------------
    gemm_f16<1><<<dim3(3072 / 128, VV / 128), 256, 0, stream>>>(
        preh, Wt, out_b, (float*)d_out, HH, VV, 3008);
}

// Round 3
// 8389.881 us; speedup vs baseline: 1.7105x; 1.4083x over previous
//
#include <hip/hip_runtime.h>
#include <hip/hip_bf16.h>
#include <cstddef>

#define BB 64
#define TXX 128
#define TYY 48
#define NSS 47
#define EE 512
#define HH 1024
#define VV 32000

typedef _Float16 f16x8 __attribute__((ext_vector_type(8)));
typedef float f32x4 __attribute__((ext_vector_type(4)));
typedef unsigned short ush;
typedef ush ushx4 __attribute__((ext_vector_type(4)));

__device__ __forceinline__ ush f2h(float x) {
    _Float16 h = (_Float16)x;
    return __builtin_bit_cast(ush, h);
}
__device__ __forceinline__ float h2f(ush u) {
    return (float)__builtin_bit_cast(_Float16, u);
}
__device__ __forceinline__ void gload16(const void* g, void* l) {
    __builtin_amdgcn_global_load_lds(
        (const __attribute__((address_space(1))) unsigned int*)g,
        (__attribute__((address_space(3))) unsigned int*)l, 16, 0, 0);
}
__device__ __forceinline__ float sigm(float x) { return 1.f / (1.f + expf(-x)); }

// ---------------------------------------------------------------------------
// Transpose + f32->f16: Wt[(v0+v)*ldT + k0+k] = f16(W[(k0+k)*ldW + v0+v])
// grid (Ncols/32, Krows/32), 256 threads.
// ---------------------------------------------------------------------------
__global__ __launch_bounds__(256) void transpose_w(
    const float* __restrict__ W, ush* __restrict__ Wt, int ldW, int ldT)
{
    __shared__ float t[32][33];
    int v0 = blockIdx.x * 32, k0 = blockIdx.y * 32;
    int tv = threadIdx.x & 31, tk = threadIdx.x >> 5;
    #pragma unroll
    for (int i = 0; i < 4; i++) {
        int k = tk * 4 + i;
        t[k][tv] = W[(size_t)(k0 + k) * ldW + v0 + tv];
    }
    __syncthreads();
    #pragma unroll
    for (int i = 0; i < 4; i++) {
        int v = tk * 4 + i;
        Wt[(size_t)(v0 + v) * ldT + k0 + tv] = f2h(t[tv][v]);
    }
}

// ---------------------------------------------------------------------------
// Embedding gather + f16 convert. Row r = t*64 + b <- token tok[b*tokld + t].
// Rows with t >= tmax write 0. Each thread: 8 consecutive k of one row.
// ---------------------------------------------------------------------------
__global__ __launch_bounds__(256) void gather_emb(
    const float* __restrict__ emb, const int* __restrict__ tok,
    ush* __restrict__ out, int tokld, int tmax)
{
    int i = blockIdx.x * 256 + threadIdx.x;
    int r = i >> 6, kq = (i & 63) * 8;
    int t = r >> 6, b = r & 63;
    ush v[8];
    if (t < tmax) {
        int tk = tok[b * tokld + t];
        const float* e = emb + (size_t)tk * EE + kq;
        #pragma unroll
        for (int j = 0; j < 8; j++) v[j] = f2h(e[j]);
    } else {
        #pragma unroll
        for (int j = 0; j < 8; j++) v[j] = 0;
    }
    *reinterpret_cast<f16x8*>(&out[(size_t)r * EE + kq]) =
        *reinterpret_cast<f16x8*>(v);
}

// ---------------------------------------------------------------------------
// f16 MFMA GEMM: C = A @ Bt^T (+bias). A [M][lda] f16, Bt [N][K] f16.
// 128x128 tile, 4 waves, 4x4 frags of 16x16x32. MODE:
//  0: f32 C row-major [Mvalid][Nld], +bias if non-null
//  1: out-projection: out[b][s][v] permute + bias, guard row<3008
//  2: f16 C row-major [Mvalid][Nld]
//  3: f16 preh: rows sstep*64.., tanh(acc+bias), guard row<64
// ---------------------------------------------------------------------------
template <int MODE>
__global__ __launch_bounds__(256) void gemm_f16(
    const ush* __restrict__ A, int lda, const ush* __restrict__ Bt,
    const float* __restrict__ bias, void* __restrict__ Cv,
    int K, int Nld, int Mvalid, int sstep)
{
    __shared__ ush As[128 * 64];
    __shared__ ush Bs[128 * 64];
    const int tid = threadIdx.x;
    const int lane = tid & 63;
    const int w = tid >> 6;
    const int wm = w >> 1, wn = w & 1;
    const int m0 = blockIdx.x * 128;
    const int n0 = blockIdx.y * 128;

    f32x4 acc[4][4] = {};
    const int srow = w * 32 + (lane >> 3);
    const int skoff = (lane & 7) * 8;

    for (int kb = 0; kb < K; kb += 64) {
        #pragma unroll
        for (int c = 0; c < 4; c++) {
            const ush* ga = A + (size_t)(m0 + srow + c * 8) * lda + kb + skoff;
            gload16(ga, &As[(w * 4 + c) * 512]);
        }
        #pragma unroll
        for (int c = 0; c < 4; c++) {
            const ush* gb = Bt + (size_t)(n0 + srow + c * 8) * K + kb + skoff;
            gload16(gb, &Bs[(w * 4 + c) * 512]);
        }
        __syncthreads();

        #pragma unroll
        for (int kw = 0; kw < 2; kw++) {
            const int koff = kw * 32 + (lane >> 4) * 8;
            f16x8 af[4], bf[4];
            #pragma unroll
            for (int m = 0; m < 4; m++)
                af[m] = *(const f16x8*)&As[(wm * 64 + m * 16 + (lane & 15)) * 64 + koff];
            #pragma unroll
            for (int n = 0; n < 4; n++)
                bf[n] = *(const f16x8*)&Bs[(wn * 64 + n * 16 + (lane & 15)) * 64 + koff];
            #pragma unroll
            for (int m = 0; m < 4; m++)
                #pragma unroll
                for (int n = 0; n < 4; n++)
                    acc[m][n] = __builtin_amdgcn_mfma_f32_16x16x32_f16(
                        af[m], bf[n], acc[m][n], 0, 0, 0);
        }
        __syncthreads();
    }

    #pragma unroll
    for (int n = 0; n < 4; n++) {
        int v = n0 + wn * 64 + n * 16 + (lane & 15);
        float bs = (MODE == 1 || MODE == 3) ? bias[v]
                 : ((MODE == 0 && bias) ? bias[v] : 0.f);
        #pragma unroll
        for (int m = 0; m < 4; m++) {
            int rbase = m0 + wm * 64 + m * 16 + (lane >> 4) * 4;
            #pragma unroll
            for (int r = 0; r < 4; r++) {
                int row = rbase + r;
                float val = acc[m][n][r] + bs;
                if (MODE == 1) {
                    if (row < 3008) {
                        int b = row & 63, s = row >> 6;
                        ((float*)Cv)[((size_t)b * NSS + s) * VV + v] = val;
                    }
                } else if (MODE == 0) {
                    if (row < Mvalid) ((float*)Cv)[(size_t)row * Nld + v] = val;
                } else if (MODE == 2) {
                    if (row < Mvalid) ((ush*)Cv)[(size_t)row * Nld + v] = f2h(val);
                } else {  // MODE 3
                    if (row < 64)
                        ((ush*)Cv)[((size_t)(sstep * 64 + row)) * 1024 + v] = f2h(tanhf(val));
                }
            }
        }
    }
}

// ---------------------------------------------------------------------------
// Fused LSTM step: z = h16 @ Wh^T + Gx + bias; gates; update c; write h16.
// Grid 64 blocks: block j computes hidden slice cc = j*16..j*16+15 for ALL
// four gates (n-frags = gates). 4 waves: wave w = rows w*16..w*16+15.
// hsrc/hdst: [128][2048] comb buffers (h in cols 0..1023). c: f32 [64][1024].
// Gx pre-offset to this step: f16 [64][4096] (col = g*1024 + cc).
// ---------------------------------------------------------------------------
template <int ISENC>
__global__ __launch_bounds__(256) void fused_step(
    const ush* __restrict__ hsrc, ush* __restrict__ hdst,
    const ush* __restrict__ Wh, const ush* __restrict__ Gx,
    const float* __restrict__ bi, const float* __restrict__ bfg,
    const float* __restrict__ bo, const float* __restrict__ bc,
    float* __restrict__ c, ush* __restrict__ enc_slot)
{
    __shared__ ush As[64 * 64];
    __shared__ ush Ws[64 * 64];
    const int j = blockIdx.x;
    const int tid = threadIdx.x;
    const int lane = tid & 63;
    const int w = tid >> 6;

    f32x4 acc[4] = {};   // one per gate
    const int r8 = lane >> 3;
    const int skoff = (lane & 7) * 8;

    for (int kb = 0; kb < 1024; kb += 64) {
        #pragma unroll
        for (int c8 = 0; c8 < 2; c8++) {
            int row = w * 16 + c8 * 8 + r8;
            gload16(hsrc + (size_t)row * 2048 + kb + skoff,
                    &As[(w * 2 + c8) * 512]);
            int wrow = row;                     // 0..63
            int g = wrow >> 4, cc = wrow & 15;
            gload16(Wh + (size_t)(g * 1024 + j * 16 + cc) * 1024 + kb + skoff,
                    &Ws[(w * 2 + c8) * 512]);
        }
        __syncthreads();

        #pragma unroll
        for (int kw = 0; kw < 2; kw++) {
            const int koff = kw * 32 + (lane >> 4) * 8;
            f16x8 af = *(const f16x8*)&As[(w * 16 + (lane & 15)) * 64 + koff];
            #pragma unroll
            for (int g = 0; g < 4; g++) {
                f16x8 bf = *(const f16x8*)&Ws[(g * 16 + (lane & 15)) * 64 + koff];
                acc[g] = __builtin_amdgcn_mfma_f32_16x16x32_f16(af, bf, acc[g], 0, 0, 0);
            }
        }
        __syncthreads();
    }

    // epilogue: lane holds rows (lane>>4)*4+r of wave's block, col cc
    const int cc = j * 16 + (lane & 15);
    const float Bi = bi[cc], Bf = bfg[cc], Bo = bo[cc], Bc = bc[cc];
    #pragma unroll
    for (int r = 0; r < 4; r++) {
        int row = w * 16 + (lane >> 4) * 4 + r;
        const ush* gx = Gx + (size_t)row * 4096;
        float zi = acc[0][r] + Bi + h2f(gx[cc]);
        float zf = acc[1][r] + Bf + h2f(gx[1024 + cc]);
        float zo = acc[2][r] + Bo + h2f(gx[2048 + cc]);
        float zc = acc[3][r] + Bc + h2f(gx[3072 + cc]);
        float F = sigm(zf), I = sigm(zi), O = sigm(zo), G = tanhf(zc);
        size_t ci = (size_t)row * 1024 + cc;
        float cn = F * c[ci] + I * G;
        c[ci] = cn;
        float hn = O * tanhf(cn);
        ush hh = f2h(hn);
        hdst[(size_t)row * 2048 + cc] = hh;
        if (ISENC) enc_slot[ci] = hh;
    }
}

// ---------------------------------------------------------------------------
// Attention: per batch row b. q f32 [64][1024] (bias included).
// enc16 f16 [128][64][1024]. ctx -> f16 into ctxdst[b*2048 + h] (comb ctx half).
// ---------------------------------------------------------------------------
__global__ __launch_bounds__(256) void attn_kernel(
    const float* __restrict__ qbuf, const ush* __restrict__ enc16,
    ush* __restrict__ ctxdst)
{
    int b = blockIdx.x;
    int tid = threadIdx.x;
    __shared__ float q[1024];
    __shared__ float sc[128];
    __shared__ float smax_s, ssum_s;

    for (int i = tid; i < 1024; i += 256) q[i] = qbuf[(size_t)b * 1024 + i];
    __syncthreads();

    int wave = tid >> 6, lane = tid & 63;
    for (int i = 0; i < 32; i++) {
        int t = wave * 32 + i;
        const ush* e = enc16 + ((size_t)t * 64 + b) * 1024;
        float s = 0.f;
        #pragma unroll
        for (int jj = 0; jj < 16; jj++) s += q[lane + jj * 64] * h2f(e[lane + jj * 64]);
        #pragma unroll
        for (int o = 32; o > 0; o >>= 1) s += __shfl_down(s, o, 64);
        if (lane == 0) sc[t] = s;
    }
    __syncthreads();

    if (wave == 0) {
        float v = fmaxf(sc[lane], sc[lane + 64]);
        #pragma unroll
        for (int o = 32; o > 0; o >>= 1) v = fmaxf(v, __shfl_down(v, o, 64));
        if (lane == 0) smax_s = v;
    }
    __syncthreads();
    float mx = smax_s;
    if (wave == 0) {
        float e0 = expf(sc[lane] - mx), e1 = expf(sc[lane + 64] - mx);
        sc[lane] = e0; sc[lane + 64] = e1;
        float v = e0 + e1;
        #pragma unroll
        for (int o = 32; o > 0; o >>= 1) v += __shfl_down(v, o, 64);
        if (lane == 0) ssum_s = v;
    }
    __syncthreads();
    float inv = 1.f / ssum_s;

    int h0 = tid * 4;
    float a0 = 0.f, a1 = 0.f, a2 = 0.f, a3 = 0.f;
    for (int t = 0; t < 128; t++) {
        float a = sc[t] * inv;
        ushx4 ev = *reinterpret_cast<const ushx4*>(
            enc16 + ((size_t)t * 64 + b) * 1024 + h0);
        a0 += a * h2f(ev[0]); a1 += a * h2f(ev[1]);
        a2 += a * h2f(ev[2]); a3 += a * h2f(ev[3]);
    }
    ushx4 o = {f2h(a0), f2h(a1), f2h(a2), f2h(a3)};
    *reinterpret_cast<ushx4*>(&ctxdst[(size_t)b * 2048 + h0]) = o;
}

// ---------------------------------------------------------------------------
extern "C" void kernel_launch(void* const* d_in, const int* in_sizes, int n_in,
                              void* d_out, int out_size, void* d_ws, size_t ws_size,
                              hipStream_t stream)
{
    const int*   x       = (const int*)d_in[0];
    const int*   y       = (const int*)d_in[1];
    const float* enc_emb = (const float*)d_in[2];
    const float* dec_emb = (const float*)d_in[3];
    const float* encW[4] = {(const float*)d_in[4], (const float*)d_in[6],
                            (const float*)d_in[8], (const float*)d_in[10]};   // i,f,o,c
    const float* encB[4] = {(const float*)d_in[5], (const float*)d_in[7],
                            (const float*)d_in[9], (const float*)d_in[11]};
    const float* decW[4] = {(const float*)d_in[12], (const float*)d_in[14],
                            (const float*)d_in[16], (const float*)d_in[18]};
    const float* decB[4] = {(const float*)d_in[13], (const float*)d_in[15],
                            (const float*)d_in[17], (const float*)d_in[19]};
    const float* attn_w  = (const float*)d_in[20];
    const float* attn_b  = (const float*)d_in[21];
    const float* lin_w   = (const float*)d_in[22];
    const float* lin_b   = (const float*)d_in[23];
    const float* out_w   = (const float*)d_in[24];
    const float* out_b   = (const float*)d_in[25];

    float* ws = (float*)d_ws;
    float* c      = ws;                          // 65536 f
    ush*   comb0  = (ush*)(ws + 65536);          // 128*2048 ush = 131072 f
    ush*   comb1  = (ush*)(ws + 196608);         // 131072 f
    float* q      = ws + 327680;                 // 65536 f
    ush*   preh   = (ush*)(ws + 393216);         // 3072*1024 ush = 1572864 f
    ush*   enc16  = (ush*)(ws + 1966080);        // 128*64*1024 ush = 4194304 f
    ush*   Wt     = (ush*)(ws + 6160384);        // 32000*1024 ush = 16384000 f
    ush*   Whe    = (ush*)(ws + 22544384);       // 4096*1024 ush = 2097152 f
    ush*   Whd    = (ush*)(ws + 24641536);       // 2097152 f
    ush*   Wxe    = (ush*)(ws + 26738688);       // 4096*512 ush = 1048576 f
    ush*   Wxd    = (ush*)(ws + 27787264);       // 1048576 f
    ush*   attn_t = (ush*)(ws + 28835840);       // 524288 f
    ush*   lin_t  = (ush*)(ws + 29360128);       // 1048576 f  (end 30408704 f)

    // dead-before-outproj scratch lives in d_out (poisoned, we overwrite fully)
    ush* Gx_enc = (ush*)d_out;                   // 8192*4096
    ush* Gx_dec = Gx_enc + (size_t)8192 * 4096;  // 3072*4096
    ush* Xe     = Gx_dec + (size_t)3072 * 4096;  // 8192*512
    ush* Ye     = Xe + (size_t)8192 * 512;       // 3072*512

    // zero c + comb0 + comb1 (contiguous) and preh (pad rows must be 0)
    hipMemsetAsync(c, 0, (size_t)327680 * 4, stream);
    hipMemsetAsync(preh, 0, (size_t)3072 * 1024 * 2, stream);

    // ---- weight prep (f32 -> f16 transposes) ----
    transpose_w<<<dim3(VV / 32, 32), 256, 0, stream>>>(out_w, Wt, VV, HH);
    transpose_w<<<dim3(32, 32), 256, 0, stream>>>(attn_w, attn_t, HH, HH);
    transpose_w<<<dim3(32, 64), 256, 0, stream>>>(lin_w, lin_t, HH, 2048);
    for (int g = 0; g < 4; g++) {
        transpose_w<<<dim3(32, 32), 256, 0, stream>>>(
            encW[g] + (size_t)EE * HH, Whe + (size_t)g * 1024 * 1024, HH, HH);
        transpose_w<<<dim3(32, 32), 256, 0, stream>>>(
            decW[g] + (size_t)EE * HH, Whd + (size_t)g * 1024 * 1024, HH, HH);
        transpose_w<<<dim3(32, 16), 256, 0, stream>>>(
            encW[g], Wxe + (size_t)g * 1024 * 512, HH, EE);
        transpose_w<<<dim3(32, 16), 256, 0, stream>>>(
            decW[g], Wxd + (size_t)g * 1024 * 512, HH, EE);
    }

    // ---- embedding gathers ----
    gather_emb<<<dim3(2048), 256, 0, stream>>>(enc_emb, x, Xe, TXX, TXX);
    gather_emb<<<dim3(768), 256, 0, stream>>>(dec_emb, y, Ye, TYY, NSS);

    // ---- x-side gate precompute: Gx = Xe @ Wx^T ----
    gemm_f16<2><<<dim3(64, 32), 256, 0, stream>>>(
        Xe, EE, Wxe, nullptr, Gx_enc, EE, 4096, 8192, 0);
    gemm_f16<2><<<dim3(24, 32), 256, 0, stream>>>(
        Ye, EE, Wxd, nullptr, Gx_dec, EE, 4096, 3072, 0);

    ush* comb[2] = {comb0, comb1};

    // ---- encoder: 128 fused steps ----
    for (int t = 0; t < TXX; t++) {
        fused_step<1><<<dim3(64), 256, 0, stream>>>(
            comb[t & 1], comb[(t + 1) & 1], Whe,
            Gx_enc + (size_t)t * 64 * 4096,
            encB[0], encB[1], encB[2], encB[3], c,
            enc16 + (size_t)t * 65536);
    }

    // ---- decoder: 47 steps x 4 kernels ----
    for (int s = 0; s < NSS; s++) {
        int cur = s & 1, nxt = cur ^ 1;
        fused_step<0><<<dim3(64), 256, 0, stream>>>(
            comb[cur], comb[nxt], Whd,
            Gx_dec + (size_t)s * 64 * 4096,
            decB[0], decB[1], decB[2], decB[3], c, nullptr);
        gemm_f16<0><<<dim3(1, 8), 256, 0, stream>>>(
            comb[nxt], 2048, attn_t, attn_b, q, HH, HH, 64, 0);
        attn_kernel<<<dim3(64), 256, 0, stream>>>(q, enc16, comb[nxt] + 1024);
        gemm_f16<3><<<dim3(1, 8), 256, 0, stream>>>(
            comb[nxt], 2048, lin_t, lin_b, preh, 2048, HH, 64, s);
    }

    // ---- output projection ----
    gemm_f16<1><<<dim3(24, VV / 128), 256, 0, stream>>>(
        preh, HH, Wt, out_b, d_out, HH, VV, 3008, 0);
}

// Round 4
// 6587.326 us; speedup vs baseline: 2.1786x; 1.2736x over previous
//
#include <hip/hip_runtime.h>
#include <hip/hip_bf16.h>
#include <hip/hip_cooperative_groups.h>
#include <cstddef>

namespace cg = cooperative_groups;

#define BB 64
#define TXX 128
#define TYY 48
#define NSS 47
#define EE 512
#define HH 1024
#define VV 32000

typedef _Float16 f16x8 __attribute__((ext_vector_type(8)));
typedef float f32x4 __attribute__((ext_vector_type(4)));
typedef unsigned short ush;
typedef ush ushx4 __attribute__((ext_vector_type(4)));

__device__ __forceinline__ ush f2h(float x) {
    _Float16 h = (_Float16)x;
    return __builtin_bit_cast(ush, h);
}
__device__ __forceinline__ float h2f(ush u) {
    return (float)__builtin_bit_cast(_Float16, u);
}
__device__ __forceinline__ void gload16(const void* g, void* l) {
    __builtin_amdgcn_global_load_lds(
        (const __attribute__((address_space(1))) unsigned int*)g,
        (__attribute__((address_space(3))) unsigned int*)l, 16, 0, 0);
}
__device__ __forceinline__ float sigm(float x) { return 1.f / (1.f + expf(-x)); }

// ---------------------------------------------------------------------------
// Transpose + f32->f16 (unchanged)
// ---------------------------------------------------------------------------
__global__ __launch_bounds__(256) void transpose_w(
    const float* __restrict__ W, ush* __restrict__ Wt, int ldW, int ldT)
{
    __shared__ float t[32][33];
    int v0 = blockIdx.x * 32, k0 = blockIdx.y * 32;
    int tv = threadIdx.x & 31, tk = threadIdx.x >> 5;
    #pragma unroll
    for (int i = 0; i < 4; i++) {
        int k = tk * 4 + i;
        t[k][tv] = W[(size_t)(k0 + k) * ldW + v0 + tv];
    }
    __syncthreads();
    #pragma unroll
    for (int i = 0; i < 4; i++) {
        int v = tk * 4 + i;
        Wt[(size_t)(v0 + v) * ldT + k0 + tv] = f2h(t[tv][v]);
    }
}

// ---------------------------------------------------------------------------
// Embedding gather + f16 convert (unchanged)
// ---------------------------------------------------------------------------
__global__ __launch_bounds__(256) void gather_emb(
    const float* __restrict__ emb, const int* __restrict__ tok,
    ush* __restrict__ out, int tokld, int tmax)
{
    int i = blockIdx.x * 256 + threadIdx.x;
    int r = i >> 6, kq = (i & 63) * 8;
    int t = r >> 6, b = r & 63;
    ush v[8];
    if (t < tmax) {
        int tk = tok[b * tokld + t];
        const float* e = emb + (size_t)tk * EE + kq;
        #pragma unroll
        for (int j = 0; j < 8; j++) v[j] = f2h(e[j]);
    } else {
        #pragma unroll
        for (int j = 0; j < 8; j++) v[j] = 0;
    }
    *reinterpret_cast<f16x8*>(&out[(size_t)r * EE + kq]) =
        *reinterpret_cast<f16x8*>(v);
}

// ---------------------------------------------------------------------------
// f16 MFMA GEMM, 128x128 tile (unchanged). MODE 1: out-proj, MODE 2: f16 C.
// ---------------------------------------------------------------------------
template <int MODE>
__global__ __launch_bounds__(256) void gemm_f16(
    const ush* __restrict__ A, int lda, const ush* __restrict__ Bt,
    const float* __restrict__ bias, void* __restrict__ Cv,
    int K, int Nld, int Mvalid)
{
    __shared__ ush As[128 * 64];
    __shared__ ush Bs[128 * 64];
    const int tid = threadIdx.x;
    const int lane = tid & 63;
    const int w = tid >> 6;
    const int wm = w >> 1, wn = w & 1;
    const int m0 = blockIdx.x * 128;
    const int n0 = blockIdx.y * 128;

    f32x4 acc[4][4] = {};
    const int srow = w * 32 + (lane >> 3);
    const int skoff = (lane & 7) * 8;

    for (int kb = 0; kb < K; kb += 64) {
        #pragma unroll
        for (int c = 0; c < 4; c++) {
            const ush* ga = A + (size_t)(m0 + srow + c * 8) * lda + kb + skoff;
            gload16(ga, &As[(w * 4 + c) * 512]);
        }
        #pragma unroll
        for (int c = 0; c < 4; c++) {
            const ush* gb = Bt + (size_t)(n0 + srow + c * 8) * K + kb + skoff;
            gload16(gb, &Bs[(w * 4 + c) * 512]);
        }
        __syncthreads();

        #pragma unroll
        for (int kw = 0; kw < 2; kw++) {
            const int koff = kw * 32 + (lane >> 4) * 8;
            f16x8 af[4], bf[4];
            #pragma unroll
            for (int m = 0; m < 4; m++)
                af[m] = *(const f16x8*)&As[(wm * 64 + m * 16 + (lane & 15)) * 64 + koff];
            #pragma unroll
            for (int n = 0; n < 4; n++)
                bf[n] = *(const f16x8*)&Bs[(wn * 64 + n * 16 + (lane & 15)) * 64 + koff];
            #pragma unroll
            for (int m = 0; m < 4; m++)
                #pragma unroll
                for (int n = 0; n < 4; n++)
                    acc[m][n] = __builtin_amdgcn_mfma_f32_16x16x32_f16(
                        af[m], bf[n], acc[m][n], 0, 0, 0);
        }
        __syncthreads();
    }

    #pragma unroll
    for (int n = 0; n < 4; n++) {
        int v = n0 + wn * 64 + n * 16 + (lane & 15);
        float bs = (MODE == 1) ? bias[v] : 0.f;
        #pragma unroll
        for (int m = 0; m < 4; m++) {
            int rbase = m0 + wm * 64 + m * 16 + (lane >> 4) * 4;
            #pragma unroll
            for (int r = 0; r < 4; r++) {
                int row = rbase + r;
                float val = acc[m][n][r] + bs;
                if (MODE == 1) {
                    if (row < 3008) {
                        int b = row & 63, s = row >> 6;
                        ((float*)Cv)[((size_t)b * NSS + s) * VV + v] = val;
                    }
                } else {
                    if (row < Mvalid) ((ush*)Cv)[(size_t)row * Nld + v] = f2h(val);
                }
            }
        }
    }
}

// ===========================================================================
// Persistent cooperative recurrent kernel: 64 blocks x 256 threads.
// LDS tiles As/Ws are [64][128] f16, XOR-swizzled (16B slot ^= row&7) to
// kill the 16-way same-column bank conflict; swizzle applied on the GLOBAL
// source address (global_load_lds writes linearly) and on fragment reads.
// ===========================================================================
struct RecArgs {
    ush *comb0, *comb1;
    float* c;
    const ush *Whe, *Whd, *Gxe, *Gxd;
    const float *ebi, *ebf, *ebo, *ebc;
    const float *dbi, *dbf, *dbo, *dbc;
    const ush *attn_t, *lin_t;
    const float *attn_b, *lin_b;
    float* q;
    ush *enc16, *preh;
};

// Fused LSTM step: block j owns hidden cols j*16..j*16+15 for all 4 gates.
__device__ __forceinline__ void phase_step(
    int j, int w, int lane, ush* As, ush* Ws,
    const ush* __restrict__ hsrc, ush* __restrict__ hdst,
    const ush* __restrict__ Wh, const ush* __restrict__ Gx,
    const float* __restrict__ bi, const float* __restrict__ bfg,
    const float* __restrict__ bo, const float* __restrict__ bc,
    float* __restrict__ c, ush* __restrict__ enc_slot)
{
    f32x4 acc[4] = {};
    for (int kb = 0; kb < 1024; kb += 128) {
        #pragma unroll
        for (int c8 = 0; c8 < 4; c8++) {
            int s = (c8 * 4 + w) * 64 + lane;
            int r = s >> 4, scc = (s & 15) ^ (r & 7);
            gload16(hsrc + (size_t)r * 2048 + kb + scc * 8,
                    As + (size_t)(c8 * 4 + w) * 512);
        }
        #pragma unroll
        for (int c8 = 0; c8 < 4; c8++) {
            int s = (c8 * 4 + w) * 64 + lane;
            int r = s >> 4, scc = (s & 15) ^ (r & 7);
            gload16(Wh + ((size_t)((r >> 4) * 1024 + j * 16 + (r & 15))) * 1024 + kb + scc * 8,
                    Ws + (size_t)(c8 * 4 + w) * 512);
        }
        __syncthreads();
        #pragma unroll
        for (int kw = 0; kw < 4; kw++) {
            int colo = kw * 32 + (lane >> 4) * 8;
            int ar = w * 16 + (lane & 15);
            f16x8 af = *(const f16x8*)&As[(ar * 128 + colo) ^ ((ar & 7) << 3)];
            #pragma unroll
            for (int g = 0; g < 4; g++) {
                int br = g * 16 + (lane & 15);
                f16x8 bfv = *(const f16x8*)&Ws[(br * 128 + colo) ^ ((br & 7) << 3)];
                acc[g] = __builtin_amdgcn_mfma_f32_16x16x32_f16(af, bfv, acc[g], 0, 0, 0);
            }
        }
        __syncthreads();
    }

    const int cc = j * 16 + (lane & 15);
    const float Bi = bi[cc], Bf = bfg[cc], Bo = bo[cc], Bc = bc[cc];
    #pragma unroll
    for (int r = 0; r < 4; r++) {
        int row = w * 16 + (lane >> 4) * 4 + r;
        const ush* gx = Gx + (size_t)row * 4096;
        float zi = acc[0][r] + Bi + h2f(gx[cc]);
        float zf = acc[1][r] + Bf + h2f(gx[1024 + cc]);
        float zo = acc[2][r] + Bo + h2f(gx[2048 + cc]);
        float zc = acc[3][r] + Bc + h2f(gx[3072 + cc]);
        float F = sigm(zf), I = sigm(zi), O = sigm(zo), G = tanhf(zc);
        size_t ci = (size_t)row * 1024 + cc;
        float cn = F * c[ci] + I * G;
        c[ci] = cn;
        float hn = O * tanhf(cn);
        ush hh = f2h(hn);
        hdst[(size_t)row * 2048 + cc] = hh;
        if (enc_slot) enc_slot[ci] = hh;
    }
}

// q = h @ attn_w^T + attn_b ; block j computes cols j*16..j*16+15.
__device__ __forceinline__ void phase_q(
    int j, int w, int lane, ush* As, ush* Ws,
    const ush* __restrict__ hsrc, const ush* __restrict__ attn_t,
    const float* __restrict__ attn_b, float* __restrict__ q)
{
    f32x4 acc = {};
    for (int kb = 0; kb < 1024; kb += 128) {
        #pragma unroll
        for (int c8 = 0; c8 < 4; c8++) {
            int s = (c8 * 4 + w) * 64 + lane;
            int r = s >> 4, scc = (s & 15) ^ (r & 7);
            gload16(hsrc + (size_t)r * 2048 + kb + scc * 8,
                    As + (size_t)(c8 * 4 + w) * 512);
        }
        {
            int s = w * 64 + lane;
            int r = s >> 4, scc = (s & 15) ^ (r & 7);
            gload16(attn_t + (size_t)(j * 16 + r) * 1024 + kb + scc * 8,
                    Ws + (size_t)w * 512);
        }
        __syncthreads();
        #pragma unroll
        for (int kw = 0; kw < 4; kw++) {
            int colo = kw * 32 + (lane >> 4) * 8;
            int ar = w * 16 + (lane & 15);
            f16x8 af = *(const f16x8*)&As[(ar * 128 + colo) ^ ((ar & 7) << 3)];
            int br = lane & 15;
            f16x8 bfv = *(const f16x8*)&Ws[(br * 128 + colo) ^ ((br & 7) << 3)];
            acc = __builtin_amdgcn_mfma_f32_16x16x32_f16(af, bfv, acc, 0, 0, 0);
        }
        __syncthreads();
    }
    int col = j * 16 + (lane & 15);
    float bsv = attn_b[col];
    #pragma unroll
    for (int r = 0; r < 4; r++) {
        int row = w * 16 + (lane >> 4) * 4 + r;
        q[(size_t)row * 1024 + col] = acc[r] + bsv;
    }
}

// attention for batch row b = blockIdx.x
__device__ __forceinline__ void phase_attn(
    int b, int tid, ush* As, ush* Ws,
    const float* __restrict__ qbuf, const ush* __restrict__ enc16,
    ush* __restrict__ ctxdst)
{
    float* qs = (float*)As;       // 4 KB of the 16 KB As
    float* sc = (float*)Ws;       // sc[0..127], sc[128]=max, sc[129]=sum

    for (int i = tid; i < 1024; i += 256) qs[i] = qbuf[(size_t)b * 1024 + i];
    __syncthreads();

    int wave = tid >> 6, lane = tid & 63;
    for (int i = 0; i < 32; i++) {
        int t = wave * 32 + i;
        const ush* e = enc16 + ((size_t)t * 64 + b) * 1024;
        float s = 0.f;
        #pragma unroll
        for (int jj = 0; jj < 16; jj++) s += qs[lane + jj * 64] * h2f(e[lane + jj * 64]);
        #pragma unroll
        for (int o = 32; o > 0; o >>= 1) s += __shfl_down(s, o, 64);
        if (lane == 0) sc[t] = s;
    }
    __syncthreads();

    if (wave == 0) {
        float v = fmaxf(sc[lane], sc[lane + 64]);
        #pragma unroll
        for (int o = 32; o > 0; o >>= 1) v = fmaxf(v, __shfl_down(v, o, 64));
        if (lane == 0) sc[128] = v;
    }
    __syncthreads();
    float mx = sc[128];
    if (wave == 0) {
        float e0 = expf(sc[lane] - mx), e1 = expf(sc[lane + 64] - mx);
        sc[lane] = e0; sc[lane + 64] = e1;
        float v = e0 + e1;
        #pragma unroll
        for (int o = 32; o > 0; o >>= 1) v += __shfl_down(v, o, 64);
        if (lane == 0) sc[129] = v;
    }
    __syncthreads();
    float inv = 1.f / sc[129];

    int h0 = tid * 4;
    float a0 = 0.f, a1 = 0.f, a2 = 0.f, a3 = 0.f;
    for (int t = 0; t < 128; t++) {
        float a = sc[t] * inv;
        ushx4 ev = *reinterpret_cast<const ushx4*>(
            enc16 + ((size_t)t * 64 + b) * 1024 + h0);
        a0 += a * h2f(ev[0]); a1 += a * h2f(ev[1]);
        a2 += a * h2f(ev[2]); a3 += a * h2f(ev[3]);
    }
    ushx4 o = {f2h(a0), f2h(a1), f2h(a2), f2h(a3)};
    *reinterpret_cast<ushx4*>(&ctxdst[(size_t)b * 2048 + h0]) = o;
    __syncthreads();
}

// prelogits: tanh(concat(h,ctx) @ lin_w^T + lin_b); block j cols j*16..+15.
__device__ __forceinline__ void phase_lin(
    int j, int w, int lane, ush* As, ush* Ws,
    const ush* __restrict__ comb, const ush* __restrict__ lin_t,
    const float* __restrict__ lin_b, ush* __restrict__ preh, int sstep)
{
    f32x4 acc = {};
    for (int kb = 0; kb < 2048; kb += 128) {
        #pragma unroll
        for (int c8 = 0; c8 < 4; c8++) {
            int s = (c8 * 4 + w) * 64 + lane;
            int r = s >> 4, scc = (s & 15) ^ (r & 7);
            gload16(comb + (size_t)r * 2048 + kb + scc * 8,
                    As + (size_t)(c8 * 4 + w) * 512);
        }
        {
            int s = w * 64 + lane;
            int r = s >> 4, scc = (s & 15) ^ (r & 7);
            gload16(lin_t + (size_t)(j * 16 + r) * 2048 + kb + scc * 8,
                    Ws + (size_t)w * 512);
        }
        __syncthreads();
        #pragma unroll
        for (int kw = 0; kw < 4; kw++) {
            int colo = kw * 32 + (lane >> 4) * 8;
            int ar = w * 16 + (lane & 15);
            f16x8 af = *(const f16x8*)&As[(ar * 128 + colo) ^ ((ar & 7) << 3)];
            int br = lane & 15;
            f16x8 bfv = *(const f16x8*)&Ws[(br * 128 + colo) ^ ((br & 7) << 3)];
            acc = __builtin_amdgcn_mfma_f32_16x16x32_f16(af, bfv, acc, 0, 0, 0);
        }
        __syncthreads();
    }
    int col = j * 16 + (lane & 15);
    float bsv = lin_b[col];
    #pragma unroll
    for (int r = 0; r < 4; r++) {
        int row = w * 16 + (lane >> 4) * 4 + r;
        preh[((size_t)(sstep * 64 + row)) * 1024 + col] = f2h(tanhf(acc[r] + bsv));
    }
}

__global__ __launch_bounds__(256) void recurrent_all(RecArgs a)
{
    cg::grid_group grid = cg::this_grid();
    __shared__ ush As[64 * 128];
    __shared__ ush Ws[64 * 128];
    const int j = blockIdx.x;
    const int tid = threadIdx.x;
    const int w = tid >> 6, lane = tid & 63;
    ush* comb[2] = {a.comb0, a.comb1};

    // ---- encoder: 128 steps ----
    for (int t = 0; t < TXX; t++) {
        phase_step(j, w, lane, As, Ws, comb[t & 1], comb[(t + 1) & 1], a.Whe,
                   a.Gxe + (size_t)t * 64 * 4096,
                   a.ebi, a.ebf, a.ebo, a.ebc, a.c,
                   a.enc16 + (size_t)t * 65536);
        grid.sync();
    }

    // ---- decoder: 47 steps ----
    int cur = 0;
    for (int s = 0; s < NSS; s++) {
        int nxt = cur ^ 1;
        phase_step(j, w, lane, As, Ws, comb[cur], comb[nxt], a.Whd,
                   a.Gxd + (size_t)s * 64 * 4096,
                   a.dbi, a.dbf, a.dbo, a.dbc, a.c, nullptr);
        grid.sync();
        phase_q(j, w, lane, As, Ws, comb[nxt], a.attn_t, a.attn_b, a.q);
        grid.sync();
        phase_attn(j, tid, As, Ws, a.q, a.enc16, comb[nxt] + 1024);
        grid.sync();
        phase_lin(j, w, lane, As, Ws, comb[nxt], a.lin_t, a.lin_b, a.preh, s);
        // no sync needed: next phase_step touches disjoint buffers
        cur = nxt;
    }
}

// ---------------------------------------------------------------------------
extern "C" void kernel_launch(void* const* d_in, const int* in_sizes, int n_in,
                              void* d_out, int out_size, void* d_ws, size_t ws_size,
                              hipStream_t stream)
{
    const int*   x       = (const int*)d_in[0];
    const int*   y       = (const int*)d_in[1];
    const float* enc_emb = (const float*)d_in[2];
    const float* dec_emb = (const float*)d_in[3];
    const float* encW[4] = {(const float*)d_in[4], (const float*)d_in[6],
                            (const float*)d_in[8], (const float*)d_in[10]};
    const float* encB[4] = {(const float*)d_in[5], (const float*)d_in[7],
                            (const float*)d_in[9], (const float*)d_in[11]};
    const float* decW[4] = {(const float*)d_in[12], (const float*)d_in[14],
                            (const float*)d_in[16], (const float*)d_in[18]};
    const float* decB[4] = {(const float*)d_in[13], (const float*)d_in[15],
                            (const float*)d_in[17], (const float*)d_in[19]};
    const float* attn_w  = (const float*)d_in[20];
    const float* attn_b  = (const float*)d_in[21];
    const float* lin_w   = (const float*)d_in[22];
    const float* lin_b   = (const float*)d_in[23];
    const float* out_w   = (const float*)d_in[24];
    const float* out_b   = (const float*)d_in[25];

    float* ws = (float*)d_ws;
    float* c      = ws;                          // 65536 f
    ush*   comb0  = (ush*)(ws + 65536);          // 131072 f
    ush*   comb1  = (ush*)(ws + 196608);         // 131072 f
    float* q      = ws + 327680;                 // 65536 f
    ush*   preh   = (ush*)(ws + 393216);         // 1572864 f
    ush*   enc16  = (ush*)(ws + 1966080);        // 4194304 f
    ush*   Wt     = (ush*)(ws + 6160384);        // 16384000 f
    ush*   Whe    = (ush*)(ws + 22544384);       // 2097152 f
    ush*   Whd    = (ush*)(ws + 24641536);       // 2097152 f
    ush*   Wxe    = (ush*)(ws + 26738688);       // 1048576 f
    ush*   Wxd    = (ush*)(ws + 27787264);       // 1048576 f
    ush*   attn_t = (ush*)(ws + 28835840);       // 524288 f
    ush*   lin_t  = (ush*)(ws + 29360128);       // 1048576 f

    // dead-before-outproj scratch in d_out
    ush* Gx_enc = (ush*)d_out;                   // 8192*4096
    ush* Gx_dec = Gx_enc + (size_t)8192 * 4096;  // 3072*4096
    ush* Xe     = Gx_dec + (size_t)3072 * 4096;  // 8192*512
    ush* Ye     = Xe + (size_t)8192 * 512;       // 3072*512

    hipMemsetAsync(c, 0, (size_t)327680 * 4, stream);
    hipMemsetAsync(preh, 0, (size_t)3072 * 1024 * 2, stream);

    // ---- weight prep ----
    transpose_w<<<dim3(VV / 32, 32), 256, 0, stream>>>(out_w, Wt, VV, HH);
    transpose_w<<<dim3(32, 32), 256, 0, stream>>>(attn_w, attn_t, HH, HH);
    transpose_w<<<dim3(32, 64), 256, 0, stream>>>(lin_w, lin_t, HH, 2048);
    for (int g = 0; g < 4; g++) {
        transpose_w<<<dim3(32, 32), 256, 0, stream>>>(
            encW[g] + (size_t)EE * HH, Whe + (size_t)g * 1024 * 1024, HH, HH);
        transpose_w<<<dim3(32, 32), 256, 0, stream>>>(
            decW[g] + (size_t)EE * HH, Whd + (size_t)g * 1024 * 1024, HH, HH);
        transpose_w<<<dim3(32, 16), 256, 0, stream>>>(
            encW[g], Wxe + (size_t)g * 1024 * 512, HH, EE);
        transpose_w<<<dim3(32, 16), 256, 0, stream>>>(
            decW[g], Wxd + (size_t)g * 1024 * 512, HH, EE);
    }

    // ---- embedding gathers ----
    gather_emb<<<dim3(2048), 256, 0, stream>>>(enc_emb, x, Xe, TXX, TXX);
    gather_emb<<<dim3(768), 256, 0, stream>>>(dec_emb, y, Ye, TYY, NSS);

    // ---- x-side gate precompute ----
    gemm_f16<2><<<dim3(64, 32), 256, 0, stream>>>(
        Xe, EE, Wxe, nullptr, Gx_enc, EE, 4096, 8192);
    gemm_f16<2><<<dim3(24, 32), 256, 0, stream>>>(
        Ye, EE, Wxd, nullptr, Gx_dec, EE, 4096, 3072);

    // ---- persistent recurrent kernel (cooperative) ----
    RecArgs ra;
    ra.comb0 = comb0; ra.comb1 = comb1; ra.c = c;
    ra.Whe = Whe; ra.Whd = Whd; ra.Gxe = Gx_enc; ra.Gxd = Gx_dec;
    ra.ebi = encB[0]; ra.ebf = encB[1]; ra.ebo = encB[2]; ra.ebc = encB[3];
    ra.dbi = decB[0]; ra.dbf = decB[1]; ra.dbo = decB[2]; ra.dbc = decB[3];
    ra.attn_t = attn_t; ra.lin_t = lin_t; ra.attn_b = attn_b; ra.lin_b = lin_b;
    ra.q = q; ra.enc16 = enc16; ra.preh = preh;
    void* kargs[] = {&ra};
    hipLaunchCooperativeKernel((void*)recurrent_all, dim3(64), dim3(256),
                               kargs, 0, stream);

    // ---- output projection ----
    gemm_f16<1><<<dim3(24, VV / 128), 256, 0, stream>>>(
        preh, HH, Wt, out_b, d_out, HH, VV, 3008);
}